// Round 7
// baseline (398.285 us; speedup 1.0000x reference)
//
#include <hip/hip_runtime.h>
#include <hip/hip_bf16.h>
#include <math.h>

typedef __attribute__((ext_vector_type(8))) short bf16x8;
typedef __attribute__((ext_vector_type(4))) short s16x4;
typedef __attribute__((ext_vector_type(4))) float f32x4;

static __device__ __forceinline__ short f2bf(float f) {
    union { float f; unsigned u; } v; v.f = f;
    unsigned r = v.u + 0x7FFFu + ((v.u >> 16) & 1u);
    return (short)(r >> 16);
}

// pack two f32 -> two bf16 (RNE) in one instruction
static __device__ __forceinline__ unsigned cvtpk(float a, float b) {
    unsigned r;
    asm("v_cvt_pk_bf16_f32 %0, %1, %2" : "=v"(r) : "v"(a), "v"(b));
    return r;
}
// 2^x
static __device__ __forceinline__ float fexp2(float x) {
    float r;
    asm("v_exp_f32 %0, %1" : "=v"(r) : "v"(x));
    return r;
}
static __device__ __forceinline__ bf16x8 pack4(unsigned u0, unsigned u1, unsigned u2, unsigned u3) {
    union { unsigned u[4]; bf16x8 v; } x;
    x.u[0] = u0; x.u[1] = u1; x.u[2] = u2; x.u[3] = u3;
    return x.v;
}

// async global->LDS, 16B per lane; dest must be linear (base + lane*16)
#define GL2LDS16(g, s) __builtin_amdgcn_global_load_lds( \
    (const __attribute__((address_space(1))) void*)(g),  \
    (__attribute__((address_space(3))) void*)(s), 16, 0, 0)

// ---------------------------------------------------------------------------
// Weight transpose + fp32->bf16:  WT[n][k] = bf16(W[k][n]),  512x512 each
// ---------------------------------------------------------------------------
__global__ __launch_bounds__(256) void wt_kernel(
    const float* __restrict__ Wq, const float* __restrict__ Wk,
    const float* __restrict__ Wv, const float* __restrict__ Wo,
    short* __restrict__ WqT, short* __restrict__ WkT,
    short* __restrict__ WvT, short* __restrict__ WoT)
{
    __shared__ short lds[64][65];
    const float* src; short* dst;
    if (blockIdx.z == 0)      { src = Wq; dst = WqT; }
    else if (blockIdx.z == 1) { src = Wk; dst = WkT; }
    else if (blockIdx.z == 2) { src = Wv; dst = WvT; }
    else                      { src = Wo; dst = WoT; }
    const int kb = blockIdx.x * 64, nb = blockIdx.y * 64;
    const int t = threadIdx.x;
    const int c = t & 63, r0 = t >> 6;
#pragma unroll
    for (int rr = 0; rr < 16; ++rr) {
        const int r = r0 * 16 + rr;
        lds[c][r] = f2bf(src[(size_t)(kb + r) * 512 + nb + c]);
    }
    __syncthreads();
#pragma unroll
    for (int rr = 0; rr < 16; ++rr) {
        const int n = r0 * 16 + rr;
        dst[(size_t)(nb + n) * 512 + kb + c] = lds[n][c];
    }
}

// ---------------------------------------------------------------------------
// Memory slots.  Kb: [b*8+h][1064][64].  VbT: [b*8+h][64][1088] with k
// pi-permuted within each 64-page: pos = (k&15)*4 + ((k>>4)&3).
// ---------------------------------------------------------------------------
__global__ __launch_bounds__(256) void mem_kernel(
    const float* __restrict__ memK, const float* __restrict__ memV,
    short* __restrict__ Kb, short* __restrict__ VbT)
{
    const int idx = blockIdx.x * 256 + threadIdx.x;
    if (idx >= 16 * 8 * 40 * 64) return;
    {
        const int d = idx & 63;
        const int m = (idx >> 6) % 40;
        const int h = (idx / 2560) & 7;
        const int b = idx / 20480;
        Kb[(((size_t)(b * 8 + h)) * 1064 + 1024 + m) * 64 + d] =
            f2bf(8.0f * memK[m * 512 + h * 64 + d]);
    }
    {
        const int m = idx % 40;
        const int d = (idx / 40) & 63;
        const int h = (idx / 2560) & 7;
        const int b = idx / 20480;
        const int pos = 1024 + ((m & 15) << 2) + (m >> 4);   // pi within page 16
        VbT[(((size_t)(b * 8 + h)) * 64 + d) * 1088 + pos] =
            f2bf(sqrtf(40.0f) * memV[m * 512 + h * 64 + d]);
    }
}

// ---------------------------------------------------------------------------
// Fused projection GEMM v4 (Q,K,V via blockIdx.y): 2-phase dbuf pipeline.
// BM=128 BN=128 BK=32; As fp32 dbuf 32KB, Bs bf16 dbuf 16KB; chunk-XOR swz.
// ---------------------------------------------------------------------------
__global__ __launch_bounds__(256) void proj_gemm(
    const float* __restrict__ Aq, const float* __restrict__ Ak, const float* __restrict__ Av,
    const short* __restrict__ WqT, const short* __restrict__ WkT, const short* __restrict__ WvT,
    const float* __restrict__ bq, const float* __restrict__ bk, const float* __restrict__ bv,
    short* __restrict__ Qb, short* __restrict__ Kb, short* __restrict__ VbT)
{
    __shared__ float As[2][4096];   // [buf][128 rows x 32 f32], chunk-swizzled
    __shared__ short Bs[2][4096];   // [buf][128 rows x 32 bf16], chunk-swizzled

    const float* A; const short* BT; const float* bias; short* out;
    int vmode, OUTROWS;
    if (blockIdx.y == 0)      { A = Aq; BT = WqT; bias = bq; out = Qb;  vmode = 0; OUTROWS = 1024; }
    else if (blockIdx.y == 1) { A = Ak; BT = WkT; bias = bk; out = Kb;  vmode = 0; OUTROWS = 1064; }
    else                      { A = Av; BT = WvT; bias = bv; out = VbT; vmode = 1; OUTROWS = 1064; }

    const int id = blockIdx.x;
    const int mt = (id & 7) + 8 * (id >> 5);
    const int nt = (id >> 3) & 3;
    const int m0 = mt * 128, n0 = nt * 128;

    const int t = threadIdx.x;
    const int lane = t & 63, w = t >> 6;
    const int wr = w >> 1, wc = w & 1;
    const int l16 = lane & 15, g4 = lane >> 4;

    f32x4 acc[4][4];
#pragma unroll
    for (int i = 0; i < 4; ++i)
#pragma unroll
        for (int j = 0; j < 4; ++j) acc[i][j] = (f32x4){0.f, 0.f, 0.f, 0.f};

#define STAGE_P(kt_, buf_) {                                                   \
    const int k0_ = (kt_) * 32;                                                \
    _Pragma("unroll")                                                          \
    for (int p = 0; p < 4; ++p) {                                              \
        const int row = p * 32 + (t >> 3);                                     \
        const int ck = (t & 7) ^ (row & 7);                                    \
        GL2LDS16(&A[(size_t)(m0 + row) * 512 + k0_ + ck * 4],                  \
                 &As[buf_][(p * 256 + t) * 4]);                                \
    }                                                                          \
    _Pragma("unroll")                                                          \
    for (int p = 0; p < 2; ++p) {                                              \
        const int row = p * 64 + (t >> 2);                                     \
        const int ck = (t & 3) ^ (row & 3);                                    \
        GL2LDS16(&BT[(size_t)(n0 + row) * 512 + k0_ + ck * 8],                 \
                 &Bs[buf_][(p * 256 + t) * 8]);                                \
    } }

    int cur = 0;
    STAGE_P(0, 0);
    __syncthreads();

    for (int kt = 0; kt < 16; ++kt) {
        if (kt < 15) STAGE_P(kt + 1, cur ^ 1);
        const char* Ab = (const char*)As[cur];
        const char* Bb = (const char*)Bs[cur];
        bf16x8 af[4], bfr[4];
#pragma unroll
        for (int mi = 0; mi < 4; ++mi) {
            const int row = wr * 64 + mi * 16 + l16;
            const int c0 = (g4 * 2) ^ (row & 7);
            const int c1 = (g4 * 2 + 1) ^ (row & 7);
            const float4 f0 = *reinterpret_cast<const float4*>(Ab + row * 128 + c0 * 16);
            const float4 f1 = *reinterpret_cast<const float4*>(Ab + row * 128 + c1 * 16);
            af[mi] = pack4(cvtpk(f0.x, f0.y), cvtpk(f0.z, f0.w),
                           cvtpk(f1.x, f1.y), cvtpk(f1.z, f1.w));
        }
#pragma unroll
        for (int ni = 0; ni < 4; ++ni) {
            const int row = wc * 64 + ni * 16 + l16;
            const int ck = g4 ^ (row & 3);
            bfr[ni] = *reinterpret_cast<const bf16x8*>(Bb + row * 64 + ck * 16);
        }
        __builtin_amdgcn_s_setprio(1);
#pragma unroll
        for (int mi = 0; mi < 4; ++mi)
#pragma unroll
            for (int ni = 0; ni < 4; ++ni)
                acc[mi][ni] = __builtin_amdgcn_mfma_f32_16x16x32_bf16(af[mi], bfr[ni], acc[mi][ni], 0, 0, 0);
        __builtin_amdgcn_s_setprio(0);
        __syncthreads();
        cur ^= 1;
    }
#undef STAGE_P

#pragma unroll
    for (int mi = 0; mi < 4; ++mi) {
#pragma unroll
        for (int ni = 0; ni < 4; ++ni) {
            const int col = n0 + wc * 64 + ni * 16 + l16;
            const int h = col >> 6, d = col & 63;
            const float bb = bias[col];
#pragma unroll
            for (int r = 0; r < 4; ++r) {
                const int rowg = m0 + wr * 64 + mi * 16 + g4 * 4 + r;
                const int b = rowg >> 10, nn = rowg & 1023;
                const short val = f2bf(acc[mi][ni][r] + bb);
                if (vmode) {
                    const int w6 = nn & 63;
                    const int pos = (nn & ~63) + ((w6 & 15) << 2) + (w6 >> 4);
                    out[(((size_t)b * 8 + h) * 64 + d) * 1088 + pos] = val;
                } else {
                    out[(((size_t)b * 8 + h) * OUTROWS + nn) * 64 + d] = val;
                }
            }
        }
    }
}

// ---------------------------------------------------------------------------
// Flash attention v2: log2-domain softmax, wave-uniform deferred max,
// per-lane partial row sums, pi-permuted P/V (cvt_pk + b64 P stores).
// 2048 blocks (XCD-swizzled), 4 waves, 64 q-rows/block, KVBLK=64.
// ---------------------------------------------------------------------------
__global__ __launch_bounds__(256) void attn_kernel(
    const short* __restrict__ Qb, const short* __restrict__ Kb,
    const short* __restrict__ VbT, const float* __restrict__ aw,
    short* __restrict__ AO)
{
    __shared__ short Ks[64][72];
    __shared__ short Vs[64][72];       // [dv][pi(k)]
    __shared__ short Ps[4][16][72];    // [q][pi(k)] per wave

    const int n = blockIdx.x;
    const int xcd = n & 7, s_ = n >> 3, j = s_ & 7, gh = s_ >> 3;
    const int g = gh * 8 + xcd;        // 0..255 = b*16+qt
    const int h = j, qt = g & 15, b = g >> 4;
    const int bh = b * 8 + h;
    const int t = threadIdx.x;
    const int lane = t & 63, w = t >> 6;
    const int l16 = lane & 15, g4 = lane >> 4;
    const int qrow0 = qt * 64 + w * 16;
    const float C = 0.1803368801f;     // 0.125 * log2(e)

    bf16x8 qf0, qf1;
    {
        const short* qp = Qb + ((size_t)bh * 1024 + qrow0 + l16) * 64 + g4 * 8;
        qf0 = *reinterpret_cast<const bf16x8*>(qp);
        qf1 = *reinterpret_cast<const bf16x8*>(qp + 32);
    }

    f32x4 O[4];
#pragma unroll
    for (int i = 0; i < 4; ++i) O[i] = (f32x4){0.f, 0.f, 0.f, 0.f};
    float M2 = -1e30f;                 // wave-uniform running max (log2 units)
    float l_p[4] = {0.f, 0.f, 0.f, 0.f};  // per-lane partial row sums

    const int str = t >> 2;            // staging row 0..63
    const int stc = (t & 3) * 16;      // 0,16,32,48 (shorts)

    for (int kt = 0; kt < 17; ++kt) {
        const int kb = kt * 64;
        const bool useaw = (kb < 1024);
        float awc[4][4];
        if (useaw) {
#pragma unroll
            for (int r = 0; r < 4; ++r) {
                const size_t awbase = ((size_t)b * 1024 + qrow0 + g4 * 4 + r) * 1024 + kb + l16;
#pragma unroll
                for (int sub = 0; sub < 4; ++sub)
                    awc[r][sub] = aw[awbase + sub * 16] * C;
            }
        }
        {   // stage K tile [64][64] (unconditional; garbage cols masked in S)
            const short* kp = &Kb[((size_t)bh * 1064 + kb + str) * 64 + stc];
            *reinterpret_cast<bf16x8*>(&Ks[str][stc]) = *reinterpret_cast<const bf16x8*>(kp);
            *reinterpret_cast<bf16x8*>(&Ks[str][stc + 8]) = *reinterpret_cast<const bf16x8*>(kp + 8);
        }
        {   // stage V^T tile [64 dv][64 pi(k)] (unconditional; P=0 masks)
            const short* vp = &VbT[((size_t)bh * 64 + str) * 1088 + kb + stc];
            *reinterpret_cast<bf16x8*>(&Vs[str][stc]) = *reinterpret_cast<const bf16x8*>(vp);
            *reinterpret_cast<bf16x8*>(&Vs[str][stc + 8]) = *reinterpret_cast<const bf16x8*>(vp + 8);
        }
        __syncthreads();

        // QK^T: S[sub] covers k = kb+sub*16+l16, q rows qrow0+g4*4+r
        f32x4 S[4];
        __builtin_amdgcn_s_setprio(1);
#pragma unroll
        for (int sub = 0; sub < 4; ++sub) {
            bf16x8 kf0 = *reinterpret_cast<const bf16x8*>(&Ks[sub * 16 + l16][g4 * 8]);
            bf16x8 kf1 = *reinterpret_cast<const bf16x8*>(&Ks[sub * 16 + l16][32 + g4 * 8]);
            f32x4 z = {0.f, 0.f, 0.f, 0.f};
            z = __builtin_amdgcn_mfma_f32_16x16x32_bf16(qf0, kf0, z, 0, 0, 0);
            S[sub] = __builtin_amdgcn_mfma_f32_16x16x32_bf16(qf1, kf1, z, 0, 0, 0);
        }
        __builtin_amdgcn_s_setprio(0);

        const bool tail = (kb + 64 > 1064);
        float sv[4][4];
        float pm = -1e30f;
#pragma unroll
        for (int r = 0; r < 4; ++r) {
#pragma unroll
            for (int sub = 0; sub < 4; ++sub) {
                float x = S[sub][r] * (useaw ? awc[r][sub] : C);
                if (tail && (kb + sub * 16 + l16 >= 1064)) x = -1e30f;
                sv[r][sub] = x;
                pm = fmaxf(pm, x);
            }
        }
        // wave-wide max (uniform across all 64 lanes)
#pragma unroll
        for (int off = 1; off < 64; off <<= 1)
            pm = fmaxf(pm, __shfl_xor(pm, off));
        // deferred rescale (THR = 8 in log2 units -> P <= 256)
        if (__any(pm > M2 + 8.0f)) {
            const float corr = fexp2(M2 - pm);
            M2 = pm;
#pragma unroll
            for (int r = 0; r < 4; ++r) l_p[r] *= corr;
#pragma unroll
            for (int i = 0; i < 4; ++i)
#pragma unroll
                for (int r = 0; r < 4; ++r) O[i][r] *= corr;
        }
#pragma unroll
        for (int r = 0; r < 4; ++r) {
            const float p0 = fexp2(sv[r][0] - M2);
            const float p1 = fexp2(sv[r][1] - M2);
            const float p2 = fexp2(sv[r][2] - M2);
            const float p3 = fexp2(sv[r][3] - M2);
            l_p[r] += (p0 + p1) + (p2 + p3);
            int2 pk;
            pk.x = (int)cvtpk(p0, p1);
            pk.y = (int)cvtpk(p2, p3);
            *reinterpret_cast<int2*>(&Ps[w][g4 * 4 + r][l16 * 4]) = pk;
        }
        // PV
        bf16x8 pf0 = *reinterpret_cast<const bf16x8*>(&Ps[w][l16][g4 * 8]);
        bf16x8 pf1 = *reinterpret_cast<const bf16x8*>(&Ps[w][l16][32 + g4 * 8]);
        __builtin_amdgcn_s_setprio(1);
#pragma unroll
        for (int sub = 0; sub < 4; ++sub) {
            bf16x8 vf0 = *reinterpret_cast<const bf16x8*>(&Vs[sub * 16 + l16][g4 * 8]);
            bf16x8 vf1 = *reinterpret_cast<const bf16x8*>(&Vs[sub * 16 + l16][32 + g4 * 8]);
            O[sub] = __builtin_amdgcn_mfma_f32_16x16x32_bf16(pf0, vf0, O[sub], 0, 0, 0);
            O[sub] = __builtin_amdgcn_mfma_f32_16x16x32_bf16(pf1, vf1, O[sub], 0, 0, 0);
        }
        __builtin_amdgcn_s_setprio(0);
        __syncthreads();
    }
    // epilogue: reduce per-lane partials across the 16-lane group, normalize
#pragma unroll
    for (int r = 0; r < 4; ++r) {
#pragma unroll
        for (int off = 1; off < 16; off <<= 1)
            l_p[r] += __shfl_xor(l_p[r], off);
    }
#pragma unroll
    for (int r = 0; r < 4; ++r) {
        const float inv = 1.0f / l_p[r];
        const int qg = qrow0 + g4 * 4 + r;
        const size_t base = ((size_t)b * 1024 + qg) * 512 + h * 64;
#pragma unroll
        for (int sub = 0; sub < 4; ++sub)
            AO[base + sub * 16 + l16] = f2bf(O[sub][r] * inv);
    }
}

// ---------------------------------------------------------------------------
// Output GEMM v4 + bias + residual: 2-phase dbuf, BK=32, both bf16.
// ---------------------------------------------------------------------------
__global__ __launch_bounds__(256) void out_gemm(
    const short* __restrict__ A, const short* __restrict__ BT,
    const float* __restrict__ bias, const float* __restrict__ resid,
    float* __restrict__ out)
{
    __shared__ short Asm[2][4096];   // [buf][128 x 32 bf16]
    __shared__ short Bs[2][4096];

    const int id = blockIdx.x;
    const int mt = (id & 7) + 8 * (id >> 5);
    const int nt = (id >> 3) & 3;
    const int m0 = mt * 128, n0 = nt * 128;

    const int t = threadIdx.x;
    const int lane = t & 63, w = t >> 6;
    const int wr = w >> 1, wc = w & 1;
    const int l16 = lane & 15, g4 = lane >> 4;

    f32x4 acc[4][4];
#pragma unroll
    for (int i = 0; i < 4; ++i)
#pragma unroll
        for (int j = 0; j < 4; ++j) acc[i][j] = (f32x4){0.f, 0.f, 0.f, 0.f};

#define STAGE_O(kt_, buf_) {                                                   \
    const int k0_ = (kt_) * 32;                                                \
    _Pragma("unroll")                                                          \
    for (int p = 0; p < 2; ++p) {                                              \
        const int row = p * 64 + (t >> 2);                                     \
        const int ck = (t & 3) ^ (row & 3);                                    \
        GL2LDS16(&A[(size_t)(m0 + row) * 512 + k0_ + ck * 8],                  \
                 &Asm[buf_][(p * 256 + t) * 8]);                               \
        GL2LDS16(&BT[(size_t)(n0 + row) * 512 + k0_ + ck * 8],                 \
                 &Bs[buf_][(p * 256 + t) * 8]);                                \
    } }

    int cur = 0;
    STAGE_O(0, 0);
    __syncthreads();

    for (int kt = 0; kt < 16; ++kt) {
        if (kt < 15) STAGE_O(kt + 1, cur ^ 1);
        const char* Ab = (const char*)Asm[cur];
        const char* Bb = (const char*)Bs[cur];
        bf16x8 af[4], bfr[4];
#pragma unroll
        for (int mi = 0; mi < 4; ++mi) {
            const int row = wr * 64 + mi * 16 + l16;
            const int ck = g4 ^ (row & 3);
            af[mi] = *reinterpret_cast<const bf16x8*>(Ab + row * 64 + ck * 16);
        }
#pragma unroll
        for (int ni = 0; ni < 4; ++ni) {
            const int row = wc * 64 + ni * 16 + l16;
            const int ck = g4 ^ (row & 3);
            bfr[ni] = *reinterpret_cast<const bf16x8*>(Bb + row * 64 + ck * 16);
        }
        __builtin_amdgcn_s_setprio(1);
#pragma unroll
        for (int mi = 0; mi < 4; ++mi)
#pragma unroll
            for (int ni = 0; ni < 4; ++ni)
                acc[mi][ni] = __builtin_amdgcn_mfma_f32_16x16x32_bf16(af[mi], bfr[ni], acc[mi][ni], 0, 0, 0);
        __builtin_amdgcn_s_setprio(0);
        __syncthreads();
        cur ^= 1;
    }
#undef STAGE_O

#pragma unroll
    for (int mi = 0; mi < 4; ++mi) {
#pragma unroll
        for (int ni = 0; ni < 4; ++ni) {
            const int col = n0 + wc * 64 + ni * 16 + l16;
            const float bb = bias[col];
#pragma unroll
            for (int r = 0; r < 4; ++r) {
                const int rowg = m0 + wr * 64 + mi * 16 + g4 * 4 + r;
                out[(size_t)rowg * 512 + col] = acc[mi][ni][r] + bb + resid[(size_t)rowg * 512 + col];
            }
        }
    }
}

// ---------------------------------------------------------------------------
// LayerNorm in-place on d_out, one wave per 512-col row
// ---------------------------------------------------------------------------
__global__ __launch_bounds__(256) void ln_kernel(
    float* __restrict__ x, const float* __restrict__ gamma, const float* __restrict__ beta)
{
    const int row = blockIdx.x * 4 + (threadIdx.x >> 6);
    const int lane = threadIdx.x & 63;
    float* rp = x + (size_t)row * 512;
    const float4 v0 = *reinterpret_cast<const float4*>(&rp[lane * 4]);
    const float4 v1 = *reinterpret_cast<const float4*>(&rp[256 + lane * 4]);
    float s = v0.x + v0.y + v0.z + v0.w + v1.x + v1.y + v1.z + v1.w;
    float sq = v0.x * v0.x + v0.y * v0.y + v0.z * v0.z + v0.w * v0.w
             + v1.x * v1.x + v1.y * v1.y + v1.z * v1.z + v1.w * v1.w;
#pragma unroll
    for (int off = 1; off < 64; off <<= 1) {
        s += __shfl_xor(s, off);
        sq += __shfl_xor(sq, off);
    }
    const float mu = s * (1.f / 512.f);
    const float var = sq * (1.f / 512.f) - mu * mu;
    const float inv = rsqrtf(var + 1e-3f);
    const float4 g0 = *reinterpret_cast<const float4*>(&gamma[lane * 4]);
    const float4 g1 = *reinterpret_cast<const float4*>(&gamma[256 + lane * 4]);
    const float4 b0 = *reinterpret_cast<const float4*>(&beta[lane * 4]);
    const float4 b1 = *reinterpret_cast<const float4*>(&beta[256 + lane * 4]);
    float4 o0, o1;
    o0.x = (v0.x - mu) * inv * g0.x + b0.x;
    o0.y = (v0.y - mu) * inv * g0.y + b0.y;
    o0.z = (v0.z - mu) * inv * g0.z + b0.z;
    o0.w = (v0.w - mu) * inv * g0.w + b0.w;
    o1.x = (v1.x - mu) * inv * g1.x + b1.x;
    o1.y = (v1.y - mu) * inv * g1.y + b1.y;
    o1.z = (v1.z - mu) * inv * g1.z + b1.z;
    o1.w = (v1.w - mu) * inv * g1.w + b1.w;
    *reinterpret_cast<float4*>(&rp[lane * 4]) = o0;
    *reinterpret_cast<float4*>(&rp[256 + lane * 4]) = o1;
}

// ---------------------------------------------------------------------------
extern "C" void kernel_launch(void* const* d_in, const int* in_sizes, int n_in,
                              void* d_out, int out_size, void* d_ws, size_t ws_size,
                              hipStream_t stream) {
    const float* queries = (const float*)d_in[0];
    const float* keys    = (const float*)d_in[1];
    const float* values  = (const float*)d_in[2];
    const float* aw      = (const float*)d_in[3];
    const float* Wq = (const float*)d_in[4];
    const float* bq = (const float*)d_in[5];
    const float* Wk = (const float*)d_in[6];
    const float* bk = (const float*)d_in[7];
    const float* Wv = (const float*)d_in[8];
    const float* bv = (const float*)d_in[9];
    const float* Wo = (const float*)d_in[10];
    const float* bo = (const float*)d_in[11];
    const float* memK = (const float*)d_in[12];
    const float* memV = (const float*)d_in[13];
    const float* gamma = (const float*)d_in[14];
    const float* beta  = (const float*)d_in[15];
    float* out = (float*)d_out;

    char* ws = (char*)d_ws;
    short* WqT = (short*)(ws + 0);
    short* WkT = (short*)(ws + 524288);
    short* WvT = (short*)(ws + 1048576);
    short* WoT = (short*)(ws + 1572864);
    short* Qb  = (short*)(ws + 2097152);                       // 16.78 MB
    short* Kb  = (short*)(ws + 2097152 + 16777216);            // 17.43 MB
    short* VbT = (short*)(ws + 2097152 + 16777216 + 17432576); // 17.83 MB
    short* AO  = (short*)(ws + 2097152 + 16777216 + 17432576 + 17825792);

    wt_kernel<<<dim3(8, 8, 4), 256, 0, stream>>>(Wq, Wk, Wv, Wo, WqT, WkT, WvT, WoT);
    mem_kernel<<<dim3(1280), 256, 0, stream>>>(memK, memV, Kb, VbT);
    proj_gemm<<<dim3(512, 3), 256, 0, stream>>>(queries, keys, values,
                                                WqT, WkT, WvT, bq, bk, bv,
                                                Qb, Kb, VbT);
    attn_kernel<<<dim3(2048), 256, 0, stream>>>(Qb, Kb, VbT, aw, AO);
    out_gemm<<<dim3(512), 256, 0, stream>>>(AO, WoT, bo, queries, out);
    ln_kernel<<<dim3(4096), 256, 0, stream>>>(out, gamma, beta);
}